// Round 3
// baseline (400.073 us; speedup 1.0000x reference)
//
#include <hip/hip_runtime.h>

#define LL 1024
#define DD 512
#define HH 8
#define EE 64
#define LDX (LL*DD)
#define BB 16

typedef _Float16 h8 __attribute__((ext_vector_type(8)));
typedef float f4 __attribute__((ext_vector_type(4)));
typedef int i4 __attribute__((ext_vector_type(4)));

__device__ __forceinline__ f4 mfma16(h8 a, h8 b, f4 c) {
    return __builtin_amdgcn_mfma_f32_16x16x32_f16(a, b, c, 0, 0, 0);
}

// ---------------- P0: x -> xT16[s][b] ----------------
__global__ __launch_bounds__(256) void k_prep(
    const float* __restrict__ x, _Float16* __restrict__ xT)
{
    const int s = blockIdx.x * 256 + threadIdx.x;
    h8 lo, hi;
    #pragma unroll
    for (int b = 0; b < 8; ++b)  lo[b] = (_Float16)x[(size_t)b*LDX + s];
    #pragma unroll
    for (int b = 0; b < 8; ++b)  hi[b] = (_Float16)x[(size_t)(b+8)*LDX + s];
    _Float16* d = xT + (size_t)s * BB;
    *(h8*)d = lo; *(h8*)(d + 8) = hi;
}

// ---------------- P1: weights -> WT[zz*64+e][d] f16 (B-frag layout) -------
// zz: 0..7 Wk h, 8..15 Wv h, 16..23 Wq h (scaled by 1/8)
__global__ __launch_bounds__(256) void k_wprep(
    const float* __restrict__ Wq, const float* __restrict__ Wk,
    const float* __restrict__ Wv, _Float16* __restrict__ WT)
{
    const int d0 = blockIdx.x * 64;
    const int zz = blockIdx.y;
    const float* src; float sc = 1.f;
    if (zz < 8)       src = Wk + (size_t)zz*DD*EE;
    else if (zz < 16) src = Wv + (size_t)(zz-8)*DD*EE;
    else            { src = Wq + (size_t)(zz-16)*DD*EE; sc = 0.125f; }
    const int t = threadIdx.x;
    const int e = t & 63, dq = t >> 6;
    #pragma unroll
    for (int i = 0; i < 16; ++i) {
        int d = d0 + dq*16 + i;
        WT[(size_t)(zz*64 + e)*DD + d] = (_Float16)(src[(size_t)d*EE + e] * sc);
    }
}

// ---------------- P2: Wo -> f16 ----------------
__global__ __launch_bounds__(256) void k_wo16(
    const float* __restrict__ Wo, _Float16* __restrict__ Wo16)
{
    const int i = blockIdx.x * 256 + threadIdx.x;
    f4 v = ((const f4*)Wo)[i];
    #pragma unroll
    for (int j = 0; j < 4; ++j) Wo16[4*i + j] = (_Float16)v[j];
}

// ---------------- K1: merged projections C[16384,17*64] ----------------
__global__ __launch_bounds__(256) void k_qkv(
    const float* __restrict__ x, const _Float16* __restrict__ WT,
    _Float16* __restrict__ qw, _Float16* __restrict__ kw, _Float16* __restrict__ vw)
{
    const int r0 = blockIdx.x * 128;
    const int z  = blockIdx.y;            // 0..7 K, 8..15 V, 16 Q0
    _Float16* dst; int h;
    if (z < 8)       { dst = kw; h = z; }
    else if (z < 16) { dst = vw; h = z - 8; }
    else             { dst = qw; h = 0; }

    __shared__ __align__(16) _Float16 As[128][72];
    __shared__ __align__(16) _Float16 Bs[64][72];

    const int t = threadIdx.x;
    const int wv = t >> 6, lane = t & 63;
    const int m = lane & 15, qd = lane >> 4;
    const int ar = t >> 1, ac0 = (t & 1) * 32;
    const int br = t >> 2, bc0 = (t & 3) * 16;

    f4 acc[2][4] = {};

    for (int kk = 0; kk < DD; kk += 64) {
        {   // A: x (f32) -> f16 LDS
            const float* s = x + (size_t)(r0 + ar)*DD + kk + ac0;
            #pragma unroll
            for (int c = 0; c < 4; ++c) {
                f4 v0 = *(const f4*)(s + 8*c);
                f4 v1 = *(const f4*)(s + 8*c + 4);
                h8 hv;
                #pragma unroll
                for (int j = 0; j < 4; ++j) { hv[j] = (_Float16)v0[j]; hv[4+j] = (_Float16)v1[j]; }
                *(h8*)&As[ar][ac0 + 8*c] = hv;
            }
        }
        {   // B: WT rows (already [n][k])
            const _Float16* s = WT + (size_t)(z*64 + br)*DD + kk + bc0;
            *(h8*)&Bs[br][bc0]     = *(const h8*)s;
            *(h8*)&Bs[br][bc0 + 8] = *(const h8*)(s + 8);
        }
        __syncthreads();
        #pragma unroll
        for (int ks = 0; ks < 2; ++ks) {
            h8 a0 = *(const h8*)&As[32*wv +  0 + m][32*ks + 8*qd];
            h8 a1 = *(const h8*)&As[32*wv + 16 + m][32*ks + 8*qd];
            #pragma unroll
            for (int nt = 0; nt < 4; ++nt) {
                h8 bb = *(const h8*)&Bs[16*nt + m][32*ks + 8*qd];
                acc[0][nt] = mfma16(a0, bb, acc[0][nt]);
                acc[1][nt] = mfma16(a1, bb, acc[1][nt]);
            }
        }
        __syncthreads();
    }
    #pragma unroll
    for (int mt = 0; mt < 2; ++mt)
        #pragma unroll
        for (int nt = 0; nt < 4; ++nt)
            #pragma unroll
            for (int r = 0; r < 4; ++r) {
                int R = r0 + 32*wv + 16*mt + 4*qd + r;
                int b = R >> 10, l = R & 1023;
                dst[((size_t)(b*HH + h)*LL + l)*EE + 16*nt + m] = (_Float16)acc[mt][nt][r];
            }
}

// ---------------- K2: Q heads 1..7 via xT16 gather ----------------
__global__ __launch_bounds__(256) void k_qshuf(
    const _Float16* __restrict__ xT, const int* __restrict__ perms,
    const _Float16* __restrict__ WT, _Float16* __restrict__ qw)
{
    const int l0 = blockIdx.x * 4;
    const int h  = blockIdx.y + 1;
    const _Float16* Wb = WT + (size_t)((16 + h)*64)*DD;   // pre-scaled
    const int* pbase = perms + (size_t)(h-1)*LDX;

    __shared__ __align__(16) _Float16 As[64][72];
    __shared__ __align__(16) _Float16 Bs[64][72];

    const int t = threadIdx.x;
    const int wv = t >> 6, lane = t & 63;
    const int m = lane & 15, qd = lane >> 4;
    const int row  = t >> 2;
    const int llo  = row >> 4;
    const int bidx = row & 15;
    const int c0   = (t & 3) * 16;
    const int br = t >> 2, bc0 = (t & 3) * 16;

    f4 acc[4] = {};

    for (int kk = 0; kk < DD; kk += 64) {
        const int* ps = pbase + (size_t)(l0 + llo)*DD + kk + c0;
        h8 g0, g1;
        {
            i4 p0 = *(const i4*)(ps);
            i4 p1 = *(const i4*)(ps + 4);
            i4 p2 = *(const i4*)(ps + 8);
            i4 p3 = *(const i4*)(ps + 12);
            #pragma unroll
            for (int j = 0; j < 4; ++j) g0[j]     = xT[(size_t)p0[j]*BB + bidx];
            #pragma unroll
            for (int j = 0; j < 4; ++j) g0[4 + j] = xT[(size_t)p1[j]*BB + bidx];
            #pragma unroll
            for (int j = 0; j < 4; ++j) g1[j]     = xT[(size_t)p2[j]*BB + bidx];
            #pragma unroll
            for (int j = 0; j < 4; ++j) g1[4 + j] = xT[(size_t)p3[j]*BB + bidx];
        }
        *(h8*)&As[row][c0]     = g0;
        *(h8*)&As[row][c0 + 8] = g1;
        {
            const _Float16* s = Wb + (size_t)br*DD + kk + bc0;
            *(h8*)&Bs[br][bc0]     = *(const h8*)s;
            *(h8*)&Bs[br][bc0 + 8] = *(const h8*)(s + 8);
        }
        __syncthreads();
        #pragma unroll
        for (int ks = 0; ks < 2; ++ks) {
            h8 a = *(const h8*)&As[16*wv + m][32*ks + 8*qd];
            #pragma unroll
            for (int nt = 0; nt < 4; ++nt) {
                h8 bb = *(const h8*)&Bs[16*nt + m][32*ks + 8*qd];
                acc[nt] = mfma16(a, bb, acc[nt]);
            }
        }
        __syncthreads();
    }
    #pragma unroll
    for (int nt = 0; nt < 4; ++nt)
        #pragma unroll
        for (int r = 0; r < 4; ++r) {
            int b = 4*qd + r;
            qw[((size_t)(b*HH + h)*LL + l0 + wv)*EE + 16*nt + m] = (_Float16)acc[nt][r];
        }
}

// ---------------- K3: attention v2 ----------------
// Q-tile 128. Q/K frags direct from global; V transposed conflict-free; P via LDS.
__global__ __launch_bounds__(256) void k_attn(
    const _Float16* __restrict__ qw, const _Float16* __restrict__ kw,
    const _Float16* __restrict__ vw, _Float16* __restrict__ oa)
{
    const int l0 = blockIdx.x * 128;
    const int bh = blockIdx.y;
    const int b = bh >> 3, h = bh & 7;
    const _Float16* qb = qw + ((size_t)bh*LL + l0)*EE;
    const _Float16* kb = kw + (size_t)bh*LL*EE;
    const _Float16* vb = vw + (size_t)bh*LL*EE;

    __shared__ __align__(16) _Float16 Ps[128][72];
    __shared__ __align__(16) _Float16 Vts[64][72];

    const int t = threadIdx.x;
    const int wv = t >> 6, lane = t & 63;
    const int m = lane & 15, qd = lane >> 4;
    const int vkey = t & 63, vec = t >> 6;

    // Q fragments in registers (scale pre-folded into Wq)
    h8 qa[2][2];
    #pragma unroll
    for (int mt = 0; mt < 2; ++mt)
        #pragma unroll
        for (int ks = 0; ks < 2; ++ks)
            qa[mt][ks] = *(const h8*)(qb + (size_t)(32*wv + 16*mt + m)*EE + 32*ks + 8*qd);

    f4 oacc[2][4] = {};
    float lp[2][4] = {};

    for (int kt = 0; kt < 16; ++kt) {
        {   // V^T staging, conflict-free (bank = const + key/2)
            const _Float16* s = vb + (size_t)(kt*64 + vkey)*EE + 16*vec;
            h8 v0 = *(const h8*)s;
            h8 v1 = *(const h8*)(s + 8);
            #pragma unroll
            for (int i = 0; i < 8; ++i) Vts[16*vec + i][vkey]     = v0[i];
            #pragma unroll
            for (int i = 0; i < 8; ++i) Vts[16*vec + 8 + i][vkey] = v1[i];
        }
        // S = Q K^T with K frags direct from global
        f4 sacc[2][4] = {};
        #pragma unroll
        for (int ks = 0; ks < 2; ++ks)
            #pragma unroll
            for (int nt = 0; nt < 4; ++nt) {
                h8 kf = *(const h8*)(kb + (size_t)(kt*64 + 16*nt + m)*EE + 32*ks + 8*qd);
                sacc[0][nt] = mfma16(qa[0][ks], kf, sacc[0][nt]);
                sacc[1][nt] = mfma16(qa[1][ks], kf, sacc[1][nt]);
            }
        // P = exp(S) -> LDS; accumulate per-lane row-sum partials
        #pragma unroll
        for (int mt = 0; mt < 2; ++mt)
            #pragma unroll
            for (int nt = 0; nt < 4; ++nt)
                #pragma unroll
                for (int r = 0; r < 4; ++r) {
                    float e = __expf(sacc[mt][nt][r]);
                    lp[mt][r] += e;
                    Ps[32*wv + 16*mt + 4*qd + r][16*nt + m] = (_Float16)e;
                }
        __syncthreads();
        // O += P V
        #pragma unroll
        for (int ks = 0; ks < 2; ++ks) {
            h8 pa0 = *(const h8*)&Ps[32*wv +  0 + m][32*ks + 8*qd];
            h8 pa1 = *(const h8*)&Ps[32*wv + 16 + m][32*ks + 8*qd];
            #pragma unroll
            for (int nt = 0; nt < 4; ++nt) {
                h8 vf = *(const h8*)&Vts[16*nt + m][32*ks + 8*qd];
                oacc[0][nt] = mfma16(pa0, vf, oacc[0][nt]);
                oacc[1][nt] = mfma16(pa1, vf, oacc[1][nt]);
            }
        }
        __syncthreads();
    }

    // reduce row sums across the 16 m-lanes (same qd group)
    #pragma unroll
    for (int mt = 0; mt < 2; ++mt)
        #pragma unroll
        for (int r = 0; r < 4; ++r) {
            float s = lp[mt][r];
            s += __shfl_xor(s, 1, 64);
            s += __shfl_xor(s, 2, 64);
            s += __shfl_xor(s, 4, 64);
            s += __shfl_xor(s, 8, 64);
            lp[mt][r] = s;
        }

    _Float16* ob = oa + ((size_t)(b*LL + l0))*(HH*EE) + h*EE;
    #pragma unroll
    for (int mt = 0; mt < 2; ++mt)
        #pragma unroll
        for (int nt = 0; nt < 4; ++nt)
            #pragma unroll
            for (int r = 0; r < 4; ++r) {
                int row = 32*wv + 16*mt + 4*qd + r;
                ob[(size_t)row*(HH*EE) + 16*nt + m] = (_Float16)(oacc[mt][nt][r] / lp[mt][r]);
            }
}

// ---------------- K4: output projection ----------------
__global__ __launch_bounds__(256) void k_oproj(
    const _Float16* __restrict__ oa, const _Float16* __restrict__ Wo16,
    const float* __restrict__ bo, float* __restrict__ out)
{
    const int r0 = blockIdx.x * 128;
    const int d0 = blockIdx.y * 64;
    __shared__ __align__(16) _Float16 As[128][72];
    __shared__ __align__(16) _Float16 Bs[64][72];
    const int t = threadIdx.x;
    const int wv = t >> 6, lane = t & 63;
    const int m = lane & 15, qd = lane >> 4;
    const int ar = t >> 1, ac0 = (t & 1) * 32;
    const int br = t >> 2, bc0 = (t & 3) * 16;

    f4 acc[2][4] = {};
    for (int kk = 0; kk < DD; kk += 64) {
        {
            const _Float16* s = oa + (size_t)(r0 + ar)*DD + kk + ac0;
            #pragma unroll
            for (int c = 0; c < 4; ++c)
                *(h8*)&As[ar][ac0 + 8*c] = *(const h8*)(s + 8*c);
        }
        {
            const _Float16* s = Wo16 + (size_t)(d0 + br)*DD + kk + bc0;
            *(h8*)&Bs[br][bc0]     = *(const h8*)s;
            *(h8*)&Bs[br][bc0 + 8] = *(const h8*)(s + 8);
        }
        __syncthreads();
        #pragma unroll
        for (int ks = 0; ks < 2; ++ks) {
            h8 a0 = *(const h8*)&As[32*wv +  0 + m][32*ks + 8*qd];
            h8 a1 = *(const h8*)&As[32*wv + 16 + m][32*ks + 8*qd];
            #pragma unroll
            for (int nt = 0; nt < 4; ++nt) {
                h8 bb = *(const h8*)&Bs[16*nt + m][32*ks + 8*qd];
                acc[0][nt] = mfma16(a0, bb, acc[0][nt]);
                acc[1][nt] = mfma16(a1, bb, acc[1][nt]);
            }
        }
        __syncthreads();
    }
    #pragma unroll
    for (int mt = 0; mt < 2; ++mt)
        #pragma unroll
        for (int nt = 0; nt < 4; ++nt)
            #pragma unroll
            for (int r = 0; r < 4; ++r) {
                int row = 32*wv + 16*mt + 4*qd + r;
                int col = 16*nt + m;
                out[(size_t)(r0 + row)*DD + d0 + col] = acc[mt][nt][r] + bo[d0 + col];
            }
}

extern "C" void kernel_launch(void* const* d_in, const int* in_sizes, int n_in,
                              void* d_out, int out_size, void* d_ws, size_t ws_size,
                              hipStream_t stream)
{
    const float* x  = (const float*)d_in[0];
    const int*   pm = (const int*)d_in[1];
    const float* Wq = (const float*)d_in[2];
    const float* Wk = (const float*)d_in[3];
    const float* Wv = (const float*)d_in[4];
    const float* Wo = (const float*)d_in[5];
    const float* bo = (const float*)d_in[6];
    float* out = (float*)d_out;

    const size_t QS = (size_t)BB * HH * LL * EE;   // 8388608
    _Float16* q    = (_Float16*)d_ws;
    _Float16* k    = q + QS;
    _Float16* v    = k + QS;
    _Float16* oaw  = v + QS;           // [B*L, H*E]; aliased with xT
    _Float16* xT   = oaw;              // dead before k_attn writes oaw
    _Float16* WT   = oaw + QS;         // [24*64][512]
    _Float16* Wo16 = WT + (size_t)24*64*DD;

    k_prep <<<dim3(LDX/256),        256, 0, stream>>>(x, xT);
    k_wprep<<<dim3(8, 24),          256, 0, stream>>>(Wq, Wk, Wv, WT);
    k_wo16 <<<dim3(DD*DD/1024),     256, 0, stream>>>(Wo, Wo16);
    k_qkv  <<<dim3(BB*LL/128, 17),  256, 0, stream>>>(x, WT, q, k, v);
    k_qshuf<<<dim3(LL/4, HH-1),     256, 0, stream>>>(xT, pm, WT, q);
    k_attn <<<dim3(LL/128, BB*HH),  256, 0, stream>>>(q, k, v, oaw);
    k_oproj<<<dim3(BB*LL/128, DD/64), 256, 0, stream>>>(oaw, Wo16, bo, out);
}

// Round 4
// 339.277 us; speedup vs baseline: 1.1792x; 1.1792x over previous
//
#include <hip/hip_runtime.h>

#define LL 1024
#define DD 512
#define HH 8
#define EE 64
#define LDX (LL*DD)
#define BB 16

typedef _Float16 h8 __attribute__((ext_vector_type(8)));
typedef float f4 __attribute__((ext_vector_type(4)));
typedef int i4 __attribute__((ext_vector_type(4)));

__device__ __forceinline__ f4 mfma16(h8 a, h8 b, f4 c) {
    return __builtin_amdgcn_mfma_f32_16x16x32_f16(a, b, c, 0, 0, 0);
}

// ---------------- P0: x -> xT16[s][b] ----------------
__global__ __launch_bounds__(256) void k_prep(
    const float* __restrict__ x, _Float16* __restrict__ xT)
{
    const int s = blockIdx.x * 256 + threadIdx.x;
    h8 lo, hi;
    #pragma unroll
    for (int b = 0; b < 8; ++b)  lo[b] = (_Float16)x[(size_t)b*LDX + s];
    #pragma unroll
    for (int b = 0; b < 8; ++b)  hi[b] = (_Float16)x[(size_t)(b+8)*LDX + s];
    _Float16* d = xT + (size_t)s * BB;
    *(h8*)d = lo; *(h8*)(d + 8) = hi;
}

// ---------------- P1: weights -> WT[zz*64+e][d] f16 (B-frag layout) -------
__global__ __launch_bounds__(256) void k_wprep(
    const float* __restrict__ Wq, const float* __restrict__ Wk,
    const float* __restrict__ Wv, _Float16* __restrict__ WT)
{
    const int d0 = blockIdx.x * 64;
    const int zz = blockIdx.y;
    const float* src; float sc = 1.f;
    if (zz < 8)       src = Wk + (size_t)zz*DD*EE;
    else if (zz < 16) src = Wv + (size_t)(zz-8)*DD*EE;
    else            { src = Wq + (size_t)(zz-16)*DD*EE; sc = 0.125f; }
    const int t = threadIdx.x;
    const int e = t & 63, dq = t >> 6;
    #pragma unroll
    for (int i = 0; i < 16; ++i) {
        int d = d0 + dq*16 + i;
        WT[(size_t)(zz*64 + e)*DD + d] = (_Float16)(src[(size_t)d*EE + e] * sc);
    }
}

// ---------------- P2: Wo -> f16 ----------------
__global__ __launch_bounds__(256) void k_wo16(
    const float* __restrict__ Wo, _Float16* __restrict__ Wo16)
{
    const int i = blockIdx.x * 256 + threadIdx.x;
    f4 v = ((const f4*)Wo)[i];
    #pragma unroll
    for (int j = 0; j < 4; ++j) Wo16[4*i + j] = (_Float16)v[j];
}

// ---------------- K1: merged projections ----------------
__global__ __launch_bounds__(256) void k_qkv(
    const float* __restrict__ x, const _Float16* __restrict__ WT,
    _Float16* __restrict__ qw, _Float16* __restrict__ kw, _Float16* __restrict__ vw)
{
    const int r0 = blockIdx.x * 128;
    const int z  = blockIdx.y;
    _Float16* dst; int h;
    if (z < 8)       { dst = kw; h = z; }
    else if (z < 16) { dst = vw; h = z - 8; }
    else             { dst = qw; h = 0; }

    __shared__ __align__(16) _Float16 As[128][72];
    __shared__ __align__(16) _Float16 Bs[64][72];

    const int t = threadIdx.x;
    const int wv = t >> 6, lane = t & 63;
    const int m = lane & 15, qd = lane >> 4;
    const int ar = t >> 1, ac0 = (t & 1) * 32;
    const int br = t >> 2, bc0 = (t & 3) * 16;

    f4 acc[2][4] = {};

    for (int kk = 0; kk < DD; kk += 64) {
        {
            const float* s = x + (size_t)(r0 + ar)*DD + kk + ac0;
            #pragma unroll
            for (int c = 0; c < 4; ++c) {
                f4 v0 = *(const f4*)(s + 8*c);
                f4 v1 = *(const f4*)(s + 8*c + 4);
                h8 hv;
                #pragma unroll
                for (int j = 0; j < 4; ++j) { hv[j] = (_Float16)v0[j]; hv[4+j] = (_Float16)v1[j]; }
                *(h8*)&As[ar][ac0 + 8*c] = hv;
            }
        }
        {
            const _Float16* s = WT + (size_t)(z*64 + br)*DD + kk + bc0;
            *(h8*)&Bs[br][bc0]     = *(const h8*)s;
            *(h8*)&Bs[br][bc0 + 8] = *(const h8*)(s + 8);
        }
        __syncthreads();
        #pragma unroll
        for (int ks = 0; ks < 2; ++ks) {
            h8 a0 = *(const h8*)&As[32*wv +  0 + m][32*ks + 8*qd];
            h8 a1 = *(const h8*)&As[32*wv + 16 + m][32*ks + 8*qd];
            #pragma unroll
            for (int nt = 0; nt < 4; ++nt) {
                h8 bb = *(const h8*)&Bs[16*nt + m][32*ks + 8*qd];
                acc[0][nt] = mfma16(a0, bb, acc[0][nt]);
                acc[1][nt] = mfma16(a1, bb, acc[1][nt]);
            }
        }
        __syncthreads();
    }
    #pragma unroll
    for (int mt = 0; mt < 2; ++mt)
        #pragma unroll
        for (int nt = 0; nt < 4; ++nt)
            #pragma unroll
            for (int r = 0; r < 4; ++r) {
                int R = r0 + 32*wv + 16*mt + 4*qd + r;
                int b = R >> 10, l = R & 1023;
                dst[((size_t)(b*HH + h)*LL + l)*EE + 16*nt + m] = (_Float16)acc[mt][nt][r];
            }
}

// ---------------- K2: Q heads 1..7 — vectorized row-gather ----------------
// One thread gathers one full 32B xT row (all 16 batches) per k-col.
__global__ __launch_bounds__(256) void k_qshuf(
    const _Float16* __restrict__ xT, const int* __restrict__ perms,
    const _Float16* __restrict__ WT, _Float16* __restrict__ qw)
{
    const int l0 = blockIdx.x * 4;
    const int h  = blockIdx.y + 1;
    const _Float16* Wb = WT + (size_t)((16 + h)*64)*DD;
    const int* pbase = perms + (size_t)(h-1)*LDX;

    __shared__ __align__(16) _Float16 As[64][72];
    __shared__ __align__(16) _Float16 Bs[64][72];

    const int t = threadIdx.x;
    const int wv = t >> 6, lane = t & 63;
    const int m = lane & 15, qd = lane >> 4;
    const int lg = t >> 6;          // l_local 0..3 (== wave)
    const int kcol = t & 63;
    const int br = t >> 2, bc0 = (t & 3) * 16;

    f4 acc[4] = {};

    for (int kk = 0; kk < DD; kk += 64) {
        const int p = pbase[(size_t)(l0 + lg)*DD + kk + kcol];
        const _Float16* g = xT + (size_t)p * BB;
        h8 g0 = *(const h8*)g;
        h8 g1 = *(const h8*)(g + 8);
        {
            const _Float16* s = Wb + (size_t)br*DD + kk + bc0;
            *(h8*)&Bs[br][bc0]     = *(const h8*)s;
            *(h8*)&Bs[br][bc0 + 8] = *(const h8*)(s + 8);
        }
        // distribute 16 batches to 16 A-rows (2-way bank alias only)
        #pragma unroll
        for (int i = 0; i < 8; ++i) As[lg*16 + i][kcol]     = g0[i];
        #pragma unroll
        for (int i = 0; i < 8; ++i) As[lg*16 + 8 + i][kcol] = g1[i];
        __syncthreads();
        #pragma unroll
        for (int ks = 0; ks < 2; ++ks) {
            h8 a = *(const h8*)&As[16*wv + m][32*ks + 8*qd];
            #pragma unroll
            for (int nt = 0; nt < 4; ++nt) {
                h8 bb = *(const h8*)&Bs[16*nt + m][32*ks + 8*qd];
                acc[nt] = mfma16(a, bb, acc[nt]);
            }
        }
        __syncthreads();
    }
    #pragma unroll
    for (int nt = 0; nt < 4; ++nt)
        #pragma unroll
        for (int r = 0; r < 4; ++r) {
            int b = 4*qd + r;
            qw[((size_t)(b*HH + h)*LL + l0 + wv)*EE + 16*nt + m] = (_Float16)acc[nt][r];
        }
}

// ---------------- K3: attention v4 — triple-buffer K/V^T, 1 barrier/kt ----
__global__ __launch_bounds__(256) void k_attn(
    const _Float16* __restrict__ qw, const _Float16* __restrict__ kw,
    const _Float16* __restrict__ vw, _Float16* __restrict__ oa)
{
    const int l0 = blockIdx.x * 128;
    const int bh = blockIdx.y;
    const int b = bh >> 3, h = bh & 7;
    const _Float16* qb = qw + ((size_t)bh*LL + l0)*EE;
    const _Float16* kb = kw + (size_t)bh*LL*EE;
    const _Float16* vb = vw + (size_t)bh*LL*EE;

    __shared__ __align__(16) _Float16 Ks[3][64][72];
    __shared__ __align__(16) _Float16 Vts[3][64][72];
    __shared__ __align__(16) _Float16 Ps[128][72];

    const int t = threadIdx.x;
    const int wv = t >> 6, lane = t & 63;
    const int m = lane & 15, qd = lane >> 4;
    const int krow = t >> 2, kc0 = (t & 3) * 16;   // K staging map
    const int vkey = t & 63, vec = t >> 6;         // V^T staging map

    // Q fragments in registers (1/8 scale pre-folded into Wq)
    h8 qa[2][2];
    #pragma unroll
    for (int mt = 0; mt < 2; ++mt)
        #pragma unroll
        for (int ks = 0; ks < 2; ++ks)
            qa[mt][ks] = *(const h8*)(qb + (size_t)(32*wv + 16*mt + m)*EE + 32*ks + 8*qd);

    f4 oacc[2][4] = {};
    float lp[2][4] = {};

    // stage kt=0 into buf 0
    {
        const _Float16* sk = kb + (size_t)krow*EE + kc0;
        h8 k0 = *(const h8*)sk, k1 = *(const h8*)(sk + 8);
        const _Float16* sv = vb + (size_t)vkey*EE + 16*vec;
        h8 v0 = *(const h8*)sv, v1 = *(const h8*)(sv + 8);
        *(h8*)&Ks[0][krow][kc0]     = k0;
        *(h8*)&Ks[0][krow][kc0 + 8] = k1;
        #pragma unroll
        for (int i = 0; i < 8; ++i) Vts[0][16*vec + i][vkey]     = v0[i];
        #pragma unroll
        for (int i = 0; i < 8; ++i) Vts[0][16*vec + 8 + i][vkey] = v1[i];
    }
    __syncthreads();

    int pc = 0;                       // current buffer = kt%3
    for (int kt = 0; kt < 16; ++kt) {
        const int pn = (pc == 2) ? 0 : pc + 1;     // stage target
        // prefetch kt+1 (clamped; redundant at kt=15, harmless)
        const int ktn = (kt < 15) ? kt + 1 : 15;
        const _Float16* sk = kb + (size_t)(ktn*64 + krow)*EE + kc0;
        h8 kn0 = *(const h8*)sk, kn1 = *(const h8*)(sk + 8);
        const _Float16* sv = vb + (size_t)(ktn*64 + vkey)*EE + 16*vec;
        h8 vn0 = *(const h8*)sv, vn1 = *(const h8*)(sv + 8);

        // S = Q K^T from Ks[pc]
        f4 sacc[2][4] = {};
        #pragma unroll
        for (int ks = 0; ks < 2; ++ks)
            #pragma unroll
            for (int nt = 0; nt < 4; ++nt) {
                h8 kf = *(const h8*)&Ks[pc][16*nt + m][32*ks + 8*qd];
                sacc[0][nt] = mfma16(qa[0][ks], kf, sacc[0][nt]);
                sacc[1][nt] = mfma16(qa[1][ks], kf, sacc[1][nt]);
            }
        // P = exp(S) -> wave-private Ps strip; per-lane row-sum partials
        #pragma unroll
        for (int mt = 0; mt < 2; ++mt)
            #pragma unroll
            for (int nt = 0; nt < 4; ++nt)
                #pragma unroll
                for (int r = 0; r < 4; ++r) {
                    float e = __expf(sacc[mt][nt][r]);
                    lp[mt][r] += e;
                    Ps[32*wv + 16*mt + 4*qd + r][16*nt + m] = (_Float16)e;
                }
        // commit prefetched tile to buf pn (vmcnt wait lands here, after compute)
        *(h8*)&Ks[pn][krow][kc0]     = kn0;
        *(h8*)&Ks[pn][krow][kc0 + 8] = kn1;
        #pragma unroll
        for (int i = 0; i < 8; ++i) Vts[pn][16*vec + i][vkey]     = vn0[i];
        #pragma unroll
        for (int i = 0; i < 8; ++i) Vts[pn][16*vec + 8 + i][vkey] = vn1[i];
        __syncthreads();
        // O += P V from Ps + Vts[pc]
        #pragma unroll
        for (int ks = 0; ks < 2; ++ks) {
            h8 pa0 = *(const h8*)&Ps[32*wv +  0 + m][32*ks + 8*qd];
            h8 pa1 = *(const h8*)&Ps[32*wv + 16 + m][32*ks + 8*qd];
            #pragma unroll
            for (int nt = 0; nt < 4; ++nt) {
                h8 vf = *(const h8*)&Vts[pc][16*nt + m][32*ks + 8*qd];
                oacc[0][nt] = mfma16(pa0, vf, oacc[0][nt]);
                oacc[1][nt] = mfma16(pa1, vf, oacc[1][nt]);
            }
        }
        pc = pn;
    }

    #pragma unroll
    for (int mt = 0; mt < 2; ++mt)
        #pragma unroll
        for (int r = 0; r < 4; ++r) {
            float s = lp[mt][r];
            s += __shfl_xor(s, 1, 64);
            s += __shfl_xor(s, 2, 64);
            s += __shfl_xor(s, 4, 64);
            s += __shfl_xor(s, 8, 64);
            lp[mt][r] = s;
        }

    _Float16* ob = oa + ((size_t)(b*LL + l0))*(HH*EE) + h*EE;
    #pragma unroll
    for (int mt = 0; mt < 2; ++mt)
        #pragma unroll
        for (int nt = 0; nt < 4; ++nt)
            #pragma unroll
            for (int r = 0; r < 4; ++r) {
                int row = 32*wv + 16*mt + 4*qd + r;
                ob[(size_t)row*(HH*EE) + 16*nt + m] = (_Float16)(oacc[mt][nt][r] / lp[mt][r]);
            }
}

// ---------------- K4: output projection ----------------
__global__ __launch_bounds__(256) void k_oproj(
    const _Float16* __restrict__ oa, const _Float16* __restrict__ Wo16,
    const float* __restrict__ bo, float* __restrict__ out)
{
    const int r0 = blockIdx.x * 128;
    const int d0 = blockIdx.y * 64;
    __shared__ __align__(16) _Float16 As[128][72];
    __shared__ __align__(16) _Float16 Bs[64][72];
    const int t = threadIdx.x;
    const int wv = t >> 6, lane = t & 63;
    const int m = lane & 15, qd = lane >> 4;
    const int ar = t >> 1, ac0 = (t & 1) * 32;
    const int br = t >> 2, bc0 = (t & 3) * 16;

    f4 acc[2][4] = {};
    for (int kk = 0; kk < DD; kk += 64) {
        {
            const _Float16* s = oa + (size_t)(r0 + ar)*DD + kk + ac0;
            #pragma unroll
            for (int c = 0; c < 4; ++c)
                *(h8*)&As[ar][ac0 + 8*c] = *(const h8*)(s + 8*c);
        }
        {
            const _Float16* s = Wo16 + (size_t)(d0 + br)*DD + kk + bc0;
            *(h8*)&Bs[br][bc0]     = *(const h8*)s;
            *(h8*)&Bs[br][bc0 + 8] = *(const h8*)(s + 8);
        }
        __syncthreads();
        #pragma unroll
        for (int ks = 0; ks < 2; ++ks) {
            h8 a0 = *(const h8*)&As[32*wv +  0 + m][32*ks + 8*qd];
            h8 a1 = *(const h8*)&As[32*wv + 16 + m][32*ks + 8*qd];
            #pragma unroll
            for (int nt = 0; nt < 4; ++nt) {
                h8 bb = *(const h8*)&Bs[16*nt + m][32*ks + 8*qd];
                acc[0][nt] = mfma16(a0, bb, acc[0][nt]);
                acc[1][nt] = mfma16(a1, bb, acc[1][nt]);
            }
        }
        __syncthreads();
    }
    #pragma unroll
    for (int mt = 0; mt < 2; ++mt)
        #pragma unroll
        for (int nt = 0; nt < 4; ++nt)
            #pragma unroll
            for (int r = 0; r < 4; ++r) {
                int row = 32*wv + 16*mt + 4*qd + r;
                int col = 16*nt + m;
                out[(size_t)(r0 + row)*DD + d0 + col] = acc[mt][nt][r] + bo[d0 + col];
            }
}

extern "C" void kernel_launch(void* const* d_in, const int* in_sizes, int n_in,
                              void* d_out, int out_size, void* d_ws, size_t ws_size,
                              hipStream_t stream)
{
    const float* x  = (const float*)d_in[0];
    const int*   pm = (const int*)d_in[1];
    const float* Wq = (const float*)d_in[2];
    const float* Wk = (const float*)d_in[3];
    const float* Wv = (const float*)d_in[4];
    const float* Wo = (const float*)d_in[5];
    const float* bo = (const float*)d_in[6];
    float* out = (float*)d_out;

    const size_t QS = (size_t)BB * HH * LL * EE;
    _Float16* q    = (_Float16*)d_ws;
    _Float16* k    = q + QS;
    _Float16* v    = k + QS;
    _Float16* oaw  = v + QS;
    _Float16* xT   = oaw;              // alias: dead before k_attn writes oaw
    _Float16* WT   = oaw + QS;
    _Float16* Wo16 = WT + (size_t)24*64*DD;

    k_prep <<<dim3(LDX/256),        256, 0, stream>>>(x, xT);
    k_wprep<<<dim3(8, 24),          256, 0, stream>>>(Wq, Wk, Wv, WT);
    k_wo16 <<<dim3(DD*DD/1024),     256, 0, stream>>>(Wo, Wo16);
    k_qkv  <<<dim3(BB*LL/128, 17),  256, 0, stream>>>(x, WT, q, k, v);
    k_qshuf<<<dim3(LL/4, HH-1),     256, 0, stream>>>(xT, pm, WT, q);
    k_attn <<<dim3(LL/128, BB*HH),  256, 0, stream>>>(q, k, v, oaw);
    k_oproj<<<dim3(BB*LL/128, DD/64), 256, 0, stream>>>(oaw, Wo16, bo, out);
}

// Round 5
// 304.069 us; speedup vs baseline: 1.3157x; 1.1158x over previous
//
#include <hip/hip_runtime.h>

#define LL 1024
#define DD 512
#define HH 8
#define EE 64
#define LDX (LL*DD)
#define BB 16

typedef _Float16 h8 __attribute__((ext_vector_type(8)));
typedef _Float16 h4 __attribute__((ext_vector_type(4)));
typedef float f4 __attribute__((ext_vector_type(4)));
typedef int i4 __attribute__((ext_vector_type(4)));

__device__ __forceinline__ f4 mfma16(h8 a, h8 b, f4 c) {
    return __builtin_amdgcn_mfma_f32_16x16x32_f16(a, b, c, 0, 0, 0);
}

// ---------------- P0: x -> xT16[s][b] (for the gather) ----------------
__global__ __launch_bounds__(256) void k_prep(
    const float* __restrict__ x, _Float16* __restrict__ xT)
{
    const int s = blockIdx.x * 256 + threadIdx.x;
    h8 lo, hi;
    #pragma unroll
    for (int b = 0; b < 8; ++b)  lo[b] = (_Float16)x[(size_t)b*LDX + s];
    #pragma unroll
    for (int b = 0; b < 8; ++b)  hi[b] = (_Float16)x[(size_t)(b+8)*LDX + s];
    _Float16* d = xT + (size_t)s * BB;
    *(h8*)d = lo; *(h8*)(d + 8) = hi;
}

// ---------------- P0b: x -> x16 (row-major f16) ----------------
__global__ __launch_bounds__(256) void k_x16(
    const float* __restrict__ x, _Float16* __restrict__ x16)
{
    const int i = blockIdx.x * 256 + threadIdx.x;
    f4 v = ((const f4*)x)[i];
    h4 o;
    #pragma unroll
    for (int j = 0; j < 4; ++j) o[j] = (_Float16)v[j];
    *(h4*)(x16 + 4*(size_t)i) = o;
}

// ---------------- P1: weights -> WT[zz*64+e][d] f16 (B-frag layout) -------
__global__ __launch_bounds__(256) void k_wprep(
    const float* __restrict__ Wq, const float* __restrict__ Wk,
    const float* __restrict__ Wv, _Float16* __restrict__ WT)
{
    const int d0 = blockIdx.x * 64;
    const int zz = blockIdx.y;
    const float* src; float sc = 1.f;
    if (zz < 8)       src = Wk + (size_t)zz*DD*EE;
    else if (zz < 16) src = Wv + (size_t)(zz-8)*DD*EE;
    else            { src = Wq + (size_t)(zz-16)*DD*EE; sc = 0.125f; }
    const int t = threadIdx.x;
    const int e = t & 63, dq = t >> 6;
    #pragma unroll
    for (int i = 0; i < 16; ++i) {
        int d = d0 + dq*16 + i;
        WT[(size_t)(zz*64 + e)*DD + d] = (_Float16)(src[(size_t)d*EE + e] * sc);
    }
}

// ---------------- P2: Wo -> f16 ----------------
__global__ __launch_bounds__(256) void k_wo16(
    const float* __restrict__ Wo, _Float16* __restrict__ Wo16)
{
    const int i = blockIdx.x * 256 + threadIdx.x;
    f4 v = ((const f4*)Wo)[i];
    #pragma unroll
    for (int j = 0; j < 4; ++j) Wo16[4*i + j] = (_Float16)v[j];
}

// ---------------- K1: merged projections, M128xN128, pipelined -----------
// N padded to 18*64; z=17 outputs discarded.
__global__ __launch_bounds__(256) void k_qkv(
    const _Float16* __restrict__ x16, const _Float16* __restrict__ WT,
    _Float16* __restrict__ qw, _Float16* __restrict__ kw, _Float16* __restrict__ vw)
{
    const int y  = blockIdx.x;            // n-tile 0..8
    const int r0 = blockIdx.y * 128;      // m-tile

    __shared__ __align__(16) _Float16 As[2][128][72];
    __shared__ __align__(16) _Float16 Bs[2][128][72];

    const int t = threadIdx.x;
    const int wv = t >> 6, lane = t & 63;
    const int m = lane & 15, qd = lane >> 4;
    const int sr = t >> 1, sc0 = (t & 1) * 32;

    const _Float16* ax = x16 + (size_t)(r0 + sr)*DD + sc0;
    const _Float16* bx = WT  + (size_t)(y*128 + sr)*DD + sc0;

    #pragma unroll
    for (int c = 0; c < 4; ++c) {
        *(h8*)&As[0][sr][sc0 + 8*c] = *(const h8*)(ax + 8*c);
        *(h8*)&Bs[0][sr][sc0 + 8*c] = *(const h8*)(bx + 8*c);
    }
    __syncthreads();

    f4 acc[2][8] = {};
    int cur = 0;
    for (int kt = 0; kt < 8; ++kt) {
        const int alt = cur ^ 1;
        h8 an[4], bn[4];
        if (kt < 7) {
            const _Float16* a2 = ax + (kt+1)*64;
            const _Float16* b2 = bx + (kt+1)*64;
            #pragma unroll
            for (int c = 0; c < 4; ++c) {
                an[c] = *(const h8*)(a2 + 8*c);
                bn[c] = *(const h8*)(b2 + 8*c);
            }
        }
        #pragma unroll
        for (int ks = 0; ks < 2; ++ks) {
            h8 a0 = *(const h8*)&As[cur][32*wv +  0 + m][32*ks + 8*qd];
            h8 a1 = *(const h8*)&As[cur][32*wv + 16 + m][32*ks + 8*qd];
            #pragma unroll
            for (int nt = 0; nt < 8; ++nt) {
                h8 bb = *(const h8*)&Bs[cur][16*nt + m][32*ks + 8*qd];
                acc[0][nt] = mfma16(a0, bb, acc[0][nt]);
                acc[1][nt] = mfma16(a1, bb, acc[1][nt]);
            }
        }
        if (kt < 7) {
            #pragma unroll
            for (int c = 0; c < 4; ++c) {
                *(h8*)&As[alt][sr][sc0 + 8*c] = an[c];
                *(h8*)&Bs[alt][sr][sc0 + 8*c] = bn[c];
            }
            __syncthreads();
            cur = alt;
        }
    }

    #pragma unroll
    for (int nt = 0; nt < 8; ++nt) {
        const int n = y*128 + 16*nt + m;
        const int z = n >> 6, e = n & 63;     // z uniform in lane (m<16)
        if (z >= 17) continue;
        _Float16* dst; int h;
        if (z < 8)       { dst = kw; h = z; }
        else if (z < 16) { dst = vw; h = z - 8; }
        else             { dst = qw; h = 0; }
        dst += (size_t)h*LL*EE + e;
        #pragma unroll
        for (int mt = 0; mt < 2; ++mt)
            #pragma unroll
            for (int r = 0; r < 4; ++r) {
                int R = r0 + 32*wv + 16*mt + 4*qd + r;
                int b = R >> 10, l = R & 1023;
                dst[((size_t)b*HH*LL + l)*EE] = (_Float16)acc[mt][nt][r];
            }
    }
}

// ---------------- K2: Q heads 1..7 — preloaded indices + pipelined -------
__global__ __launch_bounds__(256) void k_qshuf(
    const _Float16* __restrict__ xT, const int* __restrict__ perms,
    const _Float16* __restrict__ WT, _Float16* __restrict__ qw)
{
    const int l0 = blockIdx.x * 4;
    const int h  = blockIdx.y + 1;
    const _Float16* Wb = WT + (size_t)((16 + h)*64)*DD;
    const int* pbase = perms + (size_t)(h-1)*LDX;

    __shared__ __align__(16) _Float16 As[2][64][72];
    __shared__ __align__(16) _Float16 Bs[2][64][72];

    const int t = threadIdx.x;
    const int wv = t >> 6, lane = t & 63;
    const int m = lane & 15, qd = lane >> 4;
    const int lg = t >> 6, kcol = t & 63;
    const int br = t >> 2, bc0 = (t & 3) * 16;

    int pv[8];
    #pragma unroll
    for (int kt = 0; kt < 8; ++kt)
        pv[kt] = pbase[(size_t)(l0 + lg)*DD + kt*64 + kcol];

    {
        const _Float16* g = xT + (size_t)pv[0] * BB;
        h8 g0 = *(const h8*)g, g1 = *(const h8*)(g + 8);
        const _Float16* s = Wb + (size_t)br*DD + bc0;
        *(h8*)&Bs[0][br][bc0]     = *(const h8*)s;
        *(h8*)&Bs[0][br][bc0 + 8] = *(const h8*)(s + 8);
        #pragma unroll
        for (int i = 0; i < 8; ++i) As[0][lg*16 + i][kcol]     = g0[i];
        #pragma unroll
        for (int i = 0; i < 8; ++i) As[0][lg*16 + 8 + i][kcol] = g1[i];
    }
    __syncthreads();

    f4 acc[4] = {};
    int cur = 0;
    for (int kt = 0; kt < 8; ++kt) {
        const int alt = cur ^ 1;
        h8 g0n, g1n, b0n, b1n;
        if (kt < 7) {
            const _Float16* g = xT + (size_t)pv[kt+1] * BB;
            g0n = *(const h8*)g; g1n = *(const h8*)(g + 8);
            const _Float16* s = Wb + (size_t)br*DD + (kt+1)*64 + bc0;
            b0n = *(const h8*)s; b1n = *(const h8*)(s + 8);
        }
        #pragma unroll
        for (int ks = 0; ks < 2; ++ks) {
            h8 a = *(const h8*)&As[cur][16*wv + m][32*ks + 8*qd];
            #pragma unroll
            for (int nt = 0; nt < 4; ++nt) {
                h8 bb = *(const h8*)&Bs[cur][16*nt + m][32*ks + 8*qd];
                acc[nt] = mfma16(a, bb, acc[nt]);
            }
        }
        if (kt < 7) {
            *(h8*)&Bs[alt][br][bc0]     = b0n;
            *(h8*)&Bs[alt][br][bc0 + 8] = b1n;
            #pragma unroll
            for (int i = 0; i < 8; ++i) As[alt][lg*16 + i][kcol]     = g0n[i];
            #pragma unroll
            for (int i = 0; i < 8; ++i) As[alt][lg*16 + 8 + i][kcol] = g1n[i];
            __syncthreads();
            cur = alt;
        }
    }
    #pragma unroll
    for (int nt = 0; nt < 4; ++nt)
        #pragma unroll
        for (int r = 0; r < 4; ++r) {
            int b = 4*qd + r;
            qw[((size_t)(b*HH + h)*LL + l0 + wv)*EE + 16*nt + m] = (_Float16)acc[nt][r];
        }
}

// ---------------- K3: attention v4 — triple-buffer K/V^T, 1 barrier/kt ----
__global__ __launch_bounds__(256) void k_attn(
    const _Float16* __restrict__ qw, const _Float16* __restrict__ kw,
    const _Float16* __restrict__ vw, _Float16* __restrict__ oa)
{
    const int l0 = blockIdx.x * 128;
    const int bh = blockIdx.y;
    const int b = bh >> 3, h = bh & 7;
    const _Float16* qb = qw + ((size_t)bh*LL + l0)*EE;
    const _Float16* kb = kw + (size_t)bh*LL*EE;
    const _Float16* vb = vw + (size_t)bh*LL*EE;

    __shared__ __align__(16) _Float16 Ks[3][64][72];
    __shared__ __align__(16) _Float16 Vts[3][64][72];
    __shared__ __align__(16) _Float16 Ps[128][72];

    const int t = threadIdx.x;
    const int wv = t >> 6, lane = t & 63;
    const int m = lane & 15, qd = lane >> 4;
    const int krow = t >> 2, kc0 = (t & 3) * 16;
    const int vkey = t & 63, vec = t >> 6;

    h8 qa[2][2];
    #pragma unroll
    for (int mt = 0; mt < 2; ++mt)
        #pragma unroll
        for (int ks = 0; ks < 2; ++ks)
            qa[mt][ks] = *(const h8*)(qb + (size_t)(32*wv + 16*mt + m)*EE + 32*ks + 8*qd);

    f4 oacc[2][4] = {};
    float lp[2][4] = {};

    {
        const _Float16* sk = kb + (size_t)krow*EE + kc0;
        h8 k0 = *(const h8*)sk, k1 = *(const h8*)(sk + 8);
        const _Float16* sv = vb + (size_t)vkey*EE + 16*vec;
        h8 v0 = *(const h8*)sv, v1 = *(const h8*)(sv + 8);
        *(h8*)&Ks[0][krow][kc0]     = k0;
        *(h8*)&Ks[0][krow][kc0 + 8] = k1;
        #pragma unroll
        for (int i = 0; i < 8; ++i) Vts[0][16*vec + i][vkey]     = v0[i];
        #pragma unroll
        for (int i = 0; i < 8; ++i) Vts[0][16*vec + 8 + i][vkey] = v1[i];
    }
    __syncthreads();

    int pc = 0;
    for (int kt = 0; kt < 16; ++kt) {
        const int pn = (pc == 2) ? 0 : pc + 1;
        const int ktn = (kt < 15) ? kt + 1 : 15;
        const _Float16* sk = kb + (size_t)(ktn*64 + krow)*EE + kc0;
        h8 kn0 = *(const h8*)sk, kn1 = *(const h8*)(sk + 8);
        const _Float16* sv = vb + (size_t)(ktn*64 + vkey)*EE + 16*vec;
        h8 vn0 = *(const h8*)sv, vn1 = *(const h8*)(sv + 8);

        f4 sacc[2][4] = {};
        #pragma unroll
        for (int ks = 0; ks < 2; ++ks)
            #pragma unroll
            for (int nt = 0; nt < 4; ++nt) {
                h8 kf = *(const h8*)&Ks[pc][16*nt + m][32*ks + 8*qd];
                sacc[0][nt] = mfma16(qa[0][ks], kf, sacc[0][nt]);
                sacc[1][nt] = mfma16(qa[1][ks], kf, sacc[1][nt]);
            }
        #pragma unroll
        for (int mt = 0; mt < 2; ++mt)
            #pragma unroll
            for (int nt = 0; nt < 4; ++nt)
                #pragma unroll
                for (int r = 0; r < 4; ++r) {
                    float e = __expf(sacc[mt][nt][r]);
                    lp[mt][r] += e;
                    Ps[32*wv + 16*mt + 4*qd + r][16*nt + m] = (_Float16)e;
                }
        *(h8*)&Ks[pn][krow][kc0]     = kn0;
        *(h8*)&Ks[pn][krow][kc0 + 8] = kn1;
        #pragma unroll
        for (int i = 0; i < 8; ++i) Vts[pn][16*vec + i][vkey]     = vn0[i];
        #pragma unroll
        for (int i = 0; i < 8; ++i) Vts[pn][16*vec + 8 + i][vkey] = vn1[i];
        __syncthreads();
        #pragma unroll
        for (int ks = 0; ks < 2; ++ks) {
            h8 pa0 = *(const h8*)&Ps[32*wv +  0 + m][32*ks + 8*qd];
            h8 pa1 = *(const h8*)&Ps[32*wv + 16 + m][32*ks + 8*qd];
            #pragma unroll
            for (int nt = 0; nt < 4; ++nt) {
                h8 vf = *(const h8*)&Vts[pc][16*nt + m][32*ks + 8*qd];
                oacc[0][nt] = mfma16(pa0, vf, oacc[0][nt]);
                oacc[1][nt] = mfma16(pa1, vf, oacc[1][nt]);
            }
        }
        pc = pn;
    }

    #pragma unroll
    for (int mt = 0; mt < 2; ++mt)
        #pragma unroll
        for (int r = 0; r < 4; ++r) {
            float s = lp[mt][r];
            s += __shfl_xor(s, 1, 64);
            s += __shfl_xor(s, 2, 64);
            s += __shfl_xor(s, 4, 64);
            s += __shfl_xor(s, 8, 64);
            lp[mt][r] = s;
        }

    _Float16* ob = oa + ((size_t)(b*LL + l0))*(HH*EE) + h*EE;
    #pragma unroll
    for (int mt = 0; mt < 2; ++mt)
        #pragma unroll
        for (int nt = 0; nt < 4; ++nt)
            #pragma unroll
            for (int r = 0; r < 4; ++r) {
                int row = 32*wv + 16*mt + 4*qd + r;
                ob[(size_t)row*(HH*EE) + 16*nt + m] = (_Float16)(oacc[mt][nt][r] / lp[mt][r]);
            }
}

// ---------------- K4: output projection, M128xN128, pipelined ------------
__global__ __launch_bounds__(256) void k_oproj(
    const _Float16* __restrict__ oa, const _Float16* __restrict__ Wo16,
    const float* __restrict__ bo, float* __restrict__ out)
{
    const int y  = blockIdx.x;            // n-tile 0..3
    const int r0 = blockIdx.y * 128;

    __shared__ __align__(16) _Float16 As[2][128][72];
    __shared__ __align__(16) _Float16 Bs[2][128][72];

    const int t = threadIdx.x;
    const int wv = t >> 6, lane = t & 63;
    const int m = lane & 15, qd = lane >> 4;
    const int sr = t >> 1, sc0 = (t & 1) * 32;

    const _Float16* ax = oa   + (size_t)(r0 + sr)*DD + sc0;
    const _Float16* bx = Wo16 + (size_t)(y*128 + sr)*DD + sc0;

    #pragma unroll
    for (int c = 0; c < 4; ++c) {
        *(h8*)&As[0][sr][sc0 + 8*c] = *(const h8*)(ax + 8*c);
        *(h8*)&Bs[0][sr][sc0 + 8*c] = *(const h8*)(bx + 8*c);
    }
    __syncthreads();

    f4 acc[2][8] = {};
    int cur = 0;
    for (int kt = 0; kt < 8; ++kt) {
        const int alt = cur ^ 1;
        h8 an[4], bn[4];
        if (kt < 7) {
            const _Float16* a2 = ax + (kt+1)*64;
            const _Float16* b2 = bx + (kt+1)*64;
            #pragma unroll
            for (int c = 0; c < 4; ++c) {
                an[c] = *(const h8*)(a2 + 8*c);
                bn[c] = *(const h8*)(b2 + 8*c);
            }
        }
        #pragma unroll
        for (int ks = 0; ks < 2; ++ks) {
            h8 a0 = *(const h8*)&As[cur][32*wv +  0 + m][32*ks + 8*qd];
            h8 a1 = *(const h8*)&As[cur][32*wv + 16 + m][32*ks + 8*qd];
            #pragma unroll
            for (int nt = 0; nt < 8; ++nt) {
                h8 bb = *(const h8*)&Bs[cur][16*nt + m][32*ks + 8*qd];
                acc[0][nt] = mfma16(a0, bb, acc[0][nt]);
                acc[1][nt] = mfma16(a1, bb, acc[1][nt]);
            }
        }
        if (kt < 7) {
            #pragma unroll
            for (int c = 0; c < 4; ++c) {
                *(h8*)&As[alt][sr][sc0 + 8*c] = an[c];
                *(h8*)&Bs[alt][sr][sc0 + 8*c] = bn[c];
            }
            __syncthreads();
            cur = alt;
        }
    }

    #pragma unroll
    for (int nt = 0; nt < 8; ++nt) {
        const int col = y*128 + 16*nt + m;
        const float bias = bo[col];
        #pragma unroll
        for (int mt = 0; mt < 2; ++mt)
            #pragma unroll
            for (int r = 0; r < 4; ++r) {
                int row = 32*wv + 16*mt + 4*qd + r;
                out[(size_t)(r0 + row)*DD + col] = acc[mt][nt][r] + bias;
            }
    }
}

extern "C" void kernel_launch(void* const* d_in, const int* in_sizes, int n_in,
                              void* d_out, int out_size, void* d_ws, size_t ws_size,
                              hipStream_t stream)
{
    const float* x  = (const float*)d_in[0];
    const int*   pm = (const int*)d_in[1];
    const float* Wq = (const float*)d_in[2];
    const float* Wk = (const float*)d_in[3];
    const float* Wv = (const float*)d_in[4];
    const float* Wo = (const float*)d_in[5];
    const float* bo = (const float*)d_in[6];
    float* out = (float*)d_out;

    const size_t QS = (size_t)BB * HH * LL * EE;
    _Float16* q    = (_Float16*)d_ws;
    _Float16* k    = q + QS;
    _Float16* v    = k + QS;
    _Float16* oaw  = v + QS;
    _Float16* xT   = oaw;              // alias: dead before k_attn writes oaw
    _Float16* WT   = oaw + QS;
    _Float16* Wo16 = WT + (size_t)24*64*DD;
    _Float16* x16  = (_Float16*)d_out; // scratch: dead before k_oproj writes out

    k_x16  <<<dim3(LDX*BB/1024),    256, 0, stream>>>(x, x16);
    k_prep <<<dim3(LDX/256),        256, 0, stream>>>(x, xT);
    k_wprep<<<dim3(8, 24),          256, 0, stream>>>(Wq, Wk, Wv, WT);
    k_wo16 <<<dim3(DD*DD/1024),     256, 0, stream>>>(Wo, Wo16);
    k_qkv  <<<dim3(9, BB*LL/128),   256, 0, stream>>>(x16, WT, q, k, v);
    k_qshuf<<<dim3(LL/4, HH-1),     256, 0, stream>>>(xT, pm, WT, q);
    k_attn <<<dim3(LL/128, BB*HH),  256, 0, stream>>>(q, k, v, oaw);
    k_oproj<<<dim3(DD/128, BB*LL/128), 256, 0, stream>>>(oaw, Wo16, bo, out);
}

// Round 6
// 290.379 us; speedup vs baseline: 1.3778x; 1.0471x over previous
//
#include <hip/hip_runtime.h>

#define LL 1024
#define DD 512
#define HH 8
#define EE 64
#define LDX (LL*DD)
#define BB 16

typedef _Float16 h8 __attribute__((ext_vector_type(8)));
typedef _Float16 h4 __attribute__((ext_vector_type(4)));
typedef float f4 __attribute__((ext_vector_type(4)));
typedef int i4 __attribute__((ext_vector_type(4)));

__device__ __forceinline__ f4 mfma16(h8 a, h8 b, f4 c) {
    return __builtin_amdgcn_mfma_f32_16x16x32_f16(a, b, c, 0, 0, 0);
}

// ---------------- P0: x -> xT16[s][b] (for the gather) ----------------
__global__ __launch_bounds__(256) void k_prep(
    const float* __restrict__ x, _Float16* __restrict__ xT)
{
    const int s = blockIdx.x * 256 + threadIdx.x;
    h8 lo, hi;
    #pragma unroll
    for (int b = 0; b < 8; ++b)  lo[b] = (_Float16)x[(size_t)b*LDX + s];
    #pragma unroll
    for (int b = 0; b < 8; ++b)  hi[b] = (_Float16)x[(size_t)(b+8)*LDX + s];
    _Float16* d = xT + (size_t)s * BB;
    *(h8*)d = lo; *(h8*)(d + 8) = hi;
}

// ---------------- P0b: x -> x16 (row-major f16) ----------------
__global__ __launch_bounds__(256) void k_x16(
    const float* __restrict__ x, _Float16* __restrict__ x16)
{
    const int i = blockIdx.x * 256 + threadIdx.x;
    f4 v = ((const f4*)x)[i];
    h4 o;
    #pragma unroll
    for (int j = 0; j < 4; ++j) o[j] = (_Float16)v[j];
    *(h4*)(x16 + 4*(size_t)i) = o;
}

// ---------------- P1: weights -> WT[zz*64+e][d] f16 (B-frag layout) -------
__global__ __launch_bounds__(256) void k_wprep(
    const float* __restrict__ Wq, const float* __restrict__ Wk,
    const float* __restrict__ Wv, _Float16* __restrict__ WT)
{
    const int d0 = blockIdx.x * 64;
    const int zz = blockIdx.y;
    const float* src; float sc = 1.f;
    if (zz < 8)       src = Wk + (size_t)zz*DD*EE;
    else if (zz < 16) src = Wv + (size_t)(zz-8)*DD*EE;
    else            { src = Wq + (size_t)(zz-16)*DD*EE; sc = 0.125f; }
    const int t = threadIdx.x;
    const int e = t & 63, dq = t >> 6;
    #pragma unroll
    for (int i = 0; i < 16; ++i) {
        int d = d0 + dq*16 + i;
        WT[(size_t)(zz*64 + e)*DD + d] = (_Float16)(src[(size_t)d*EE + e] * sc);
    }
}

// ---------------- P2: Wo -> f16 ----------------
__global__ __launch_bounds__(256) void k_wo16(
    const float* __restrict__ Wo, _Float16* __restrict__ Wo16)
{
    const int i = blockIdx.x * 256 + threadIdx.x;
    f4 v = ((const f4*)Wo)[i];
    #pragma unroll
    for (int j = 0; j < 4; ++j) Wo16[4*i + j] = (_Float16)v[j];
}

// ---------------- K1: merged projections, M128xN128, pipelined -----------
__global__ __launch_bounds__(256) void k_qkv(
    const _Float16* __restrict__ x16, const _Float16* __restrict__ WT,
    _Float16* __restrict__ qw, _Float16* __restrict__ kw, _Float16* __restrict__ vw)
{
    const int y  = blockIdx.x;
    const int r0 = blockIdx.y * 128;

    __shared__ __align__(16) _Float16 As[2][128][72];
    __shared__ __align__(16) _Float16 Bs[2][128][72];

    const int t = threadIdx.x;
    const int wv = t >> 6, lane = t & 63;
    const int m = lane & 15, qd = lane >> 4;
    const int sr = t >> 1, sc0 = (t & 1) * 32;

    const _Float16* ax = x16 + (size_t)(r0 + sr)*DD + sc0;
    const _Float16* bx = WT  + (size_t)(y*128 + sr)*DD + sc0;

    #pragma unroll
    for (int c = 0; c < 4; ++c) {
        *(h8*)&As[0][sr][sc0 + 8*c] = *(const h8*)(ax + 8*c);
        *(h8*)&Bs[0][sr][sc0 + 8*c] = *(const h8*)(bx + 8*c);
    }
    __syncthreads();

    f4 acc[2][8] = {};
    int cur = 0;
    for (int kt = 0; kt < 8; ++kt) {
        const int alt = cur ^ 1;
        h8 an[4], bn[4];
        if (kt < 7) {
            const _Float16* a2 = ax + (kt+1)*64;
            const _Float16* b2 = bx + (kt+1)*64;
            #pragma unroll
            for (int c = 0; c < 4; ++c) {
                an[c] = *(const h8*)(a2 + 8*c);
                bn[c] = *(const h8*)(b2 + 8*c);
            }
        }
        #pragma unroll
        for (int ks = 0; ks < 2; ++ks) {
            h8 a0 = *(const h8*)&As[cur][32*wv +  0 + m][32*ks + 8*qd];
            h8 a1 = *(const h8*)&As[cur][32*wv + 16 + m][32*ks + 8*qd];
            #pragma unroll
            for (int nt = 0; nt < 8; ++nt) {
                h8 bb = *(const h8*)&Bs[cur][16*nt + m][32*ks + 8*qd];
                acc[0][nt] = mfma16(a0, bb, acc[0][nt]);
                acc[1][nt] = mfma16(a1, bb, acc[1][nt]);
            }
        }
        if (kt < 7) {
            #pragma unroll
            for (int c = 0; c < 4; ++c) {
                *(h8*)&As[alt][sr][sc0 + 8*c] = an[c];
                *(h8*)&Bs[alt][sr][sc0 + 8*c] = bn[c];
            }
            __syncthreads();
            cur = alt;
        }
    }

    #pragma unroll
    for (int nt = 0; nt < 8; ++nt) {
        const int n = y*128 + 16*nt + m;
        const int z = n >> 6, e = n & 63;
        if (z >= 17) continue;
        _Float16* dst; int h;
        if (z < 8)       { dst = kw; h = z; }
        else if (z < 16) { dst = vw; h = z - 8; }
        else             { dst = qw; h = 0; }
        dst += (size_t)h*LL*EE + e;
        #pragma unroll
        for (int mt = 0; mt < 2; ++mt)
            #pragma unroll
            for (int r = 0; r < 4; ++r) {
                int R = r0 + 32*wv + 16*mt + 4*qd + r;
                int b = R >> 10, l = R & 1023;
                dst[((size_t)b*HH*LL + l)*EE] = (_Float16)acc[mt][nt][r];
            }
    }
}

// ---------------- K2: Q heads 1..7 — preloaded indices + pipelined -------
__global__ __launch_bounds__(256) void k_qshuf(
    const _Float16* __restrict__ xT, const int* __restrict__ perms,
    const _Float16* __restrict__ WT, _Float16* __restrict__ qw)
{
    const int l0 = blockIdx.x * 4;
    const int h  = blockIdx.y + 1;
    const _Float16* Wb = WT + (size_t)((16 + h)*64)*DD;
    const int* pbase = perms + (size_t)(h-1)*LDX;

    __shared__ __align__(16) _Float16 As[2][64][72];
    __shared__ __align__(16) _Float16 Bs[2][64][72];

    const int t = threadIdx.x;
    const int wv = t >> 6, lane = t & 63;
    const int m = lane & 15, qd = lane >> 4;
    const int lg = t >> 6, kcol = t & 63;
    const int br = t >> 2, bc0 = (t & 3) * 16;

    int pv[8];
    #pragma unroll
    for (int kt = 0; kt < 8; ++kt)
        pv[kt] = pbase[(size_t)(l0 + lg)*DD + kt*64 + kcol];

    {
        const _Float16* g = xT + (size_t)pv[0] * BB;
        h8 g0 = *(const h8*)g, g1 = *(const h8*)(g + 8);
        const _Float16* s = Wb + (size_t)br*DD + bc0;
        *(h8*)&Bs[0][br][bc0]     = *(const h8*)s;
        *(h8*)&Bs[0][br][bc0 + 8] = *(const h8*)(s + 8);
        #pragma unroll
        for (int i = 0; i < 8; ++i) As[0][lg*16 + i][kcol]     = g0[i];
        #pragma unroll
        for (int i = 0; i < 8; ++i) As[0][lg*16 + 8 + i][kcol] = g1[i];
    }
    __syncthreads();

    f4 acc[4] = {};
    int cur = 0;
    for (int kt = 0; kt < 8; ++kt) {
        const int alt = cur ^ 1;
        h8 g0n, g1n, b0n, b1n;
        if (kt < 7) {
            const _Float16* g = xT + (size_t)pv[kt+1] * BB;
            g0n = *(const h8*)g; g1n = *(const h8*)(g + 8);
            const _Float16* s = Wb + (size_t)br*DD + (kt+1)*64 + bc0;
            b0n = *(const h8*)s; b1n = *(const h8*)(s + 8);
        }
        #pragma unroll
        for (int ks = 0; ks < 2; ++ks) {
            h8 a = *(const h8*)&As[cur][16*wv + m][32*ks + 8*qd];
            #pragma unroll
            for (int nt = 0; nt < 4; ++nt) {
                h8 bb = *(const h8*)&Bs[cur][16*nt + m][32*ks + 8*qd];
                acc[nt] = mfma16(a, bb, acc[nt]);
            }
        }
        if (kt < 7) {
            *(h8*)&Bs[alt][br][bc0]     = b0n;
            *(h8*)&Bs[alt][br][bc0 + 8] = b1n;
            #pragma unroll
            for (int i = 0; i < 8; ++i) As[alt][lg*16 + i][kcol]     = g0n[i];
            #pragma unroll
            for (int i = 0; i < 8; ++i) As[alt][lg*16 + 8 + i][kcol] = g1n[i];
            __syncthreads();
            cur = alt;
        }
    }
    #pragma unroll
    for (int nt = 0; nt < 4; ++nt)
        #pragma unroll
        for (int r = 0; r < 4; ++r) {
            int b = 4*qd + r;
            qw[((size_t)(b*HH + h)*LL + l0 + wv)*EE + 16*nt + m] = (_Float16)acc[nt][r];
        }
}

// ---------------- K3: attention v5 ----------------
// Double-buffered swizzled stride-64 K/V tiles (no pad, b128-aligned,
// bank-uniform), PV before commit => 1 barrier/kt race-free with 2 buffers.
// LDS 51.2 KB -> 3 blocks/CU. Grid bh-major for XCD L2 locality.
__global__ __launch_bounds__(256, 3) void k_attn(
    const _Float16* __restrict__ qw, const _Float16* __restrict__ kw,
    const _Float16* __restrict__ vw, _Float16* __restrict__ oa)
{
    const int bh = blockIdx.x;
    const int l0 = blockIdx.y * 128;
    const int b = bh >> 3, h = bh & 7;
    const _Float16* qb = qw + ((size_t)bh*LL + l0)*EE;
    const _Float16* kb = kw + (size_t)bh*LL*EE;
    const _Float16* vb = vw + (size_t)bh*LL*EE;

    __shared__ __align__(16) _Float16 KsF[2][64*64];
    __shared__ __align__(16) _Float16 VtsF[2][64*64];
    __shared__ __align__(16) _Float16 Ps[128][72];

    const int t = threadIdx.x;
    const int wv = t >> 6, lane = t & 63;
    const int m = lane & 15, qd = lane >> 4;
    const int m7 = m & 7;
    const int krow = t >> 2, c0 = t & 3;           // K staging
    const int vkey = t & 63, vec = t >> 6;         // V staging
    const int vhi = vkey >> 3, vlo = vkey & 7;

    h8 qa[2][2];
    #pragma unroll
    for (int mt = 0; mt < 2; ++mt)
        #pragma unroll
        for (int ks = 0; ks < 2; ++ks)
            qa[mt][ks] = *(const h8*)(qb + (size_t)(32*wv + 16*mt + m)*EE + 32*ks + 8*qd);

    f4 oacc[2][4] = {};
    float lp[2][4] = {};

    {   // stage kt=0 into buf 0
        const _Float16* sk = kb + (size_t)krow*EE + 16*c0;
        h8 k0 = *(const h8*)sk, k1 = *(const h8*)(sk + 8);
        const _Float16* sv = vb + (size_t)vkey*EE + 16*vec;
        h8 v0 = *(const h8*)sv, v1 = *(const h8*)(sv + 8);
        *(h8*)&KsF[0][(krow<<6) + 8*((2*c0)     ^ (krow & 7))] = k0;
        *(h8*)&KsF[0][(krow<<6) + 8*((2*c0 + 1) ^ (krow & 7))] = k1;
        #pragma unroll
        for (int i = 0; i < 8; ++i)
            VtsF[0][((16*vec + i)<<6)     + 8*(vhi ^ i) + vlo] = v0[i];
        #pragma unroll
        for (int i = 0; i < 8; ++i)
            VtsF[0][((16*vec + 8 + i)<<6) + 8*(vhi ^ i) + vlo] = v1[i];
    }
    __syncthreads();

    for (int kt = 0; kt < 16; ++kt) {
        const int cur = kt & 1, alt = cur ^ 1;
        h8 kn0, kn1, vn0, vn1;
        if (kt < 15) {   // prefetch kt+1 into regs
            const _Float16* sk = kb + (size_t)((kt+1)*64 + krow)*EE + 16*c0;
            kn0 = *(const h8*)sk; kn1 = *(const h8*)(sk + 8);
            const _Float16* sv = vb + (size_t)((kt+1)*64 + vkey)*EE + 16*vec;
            vn0 = *(const h8*)sv; vn1 = *(const h8*)(sv + 8);
        }
        // S = Q K^T from KsF[cur] (swizzled chunks)
        f4 sacc[2][4] = {};
        #pragma unroll
        for (int ks = 0; ks < 2; ++ks)
            #pragma unroll
            for (int nt = 0; nt < 4; ++nt) {
                h8 kf = *(const h8*)&KsF[cur][((16*nt + m)<<6) + 8*((4*ks + qd) ^ m7)];
                sacc[0][nt] = mfma16(qa[0][ks], kf, sacc[0][nt]);
                sacc[1][nt] = mfma16(qa[1][ks], kf, sacc[1][nt]);
            }
        // P = exp(S) -> wave-private Ps strip; per-lane row-sum partials
        #pragma unroll
        for (int mt = 0; mt < 2; ++mt)
            #pragma unroll
            for (int nt = 0; nt < 4; ++nt)
                #pragma unroll
                for (int r = 0; r < 4; ++r) {
                    float e = __expf(sacc[mt][nt][r]);
                    lp[mt][r] += e;
                    Ps[32*wv + 16*mt + 4*qd + r][16*nt + m] = (_Float16)e;
                }
        // O += P V from Ps + VtsF[cur]  (reads of cur precede the barrier)
        #pragma unroll
        for (int ks = 0; ks < 2; ++ks) {
            h8 pa0 = *(const h8*)&Ps[32*wv +  0 + m][32*ks + 8*qd];
            h8 pa1 = *(const h8*)&Ps[32*wv + 16 + m][32*ks + 8*qd];
            #pragma unroll
            for (int nt = 0; nt < 4; ++nt) {
                h8 vf = *(const h8*)&VtsF[cur][((16*nt + m)<<6) + 8*((4*ks + qd) ^ m7)];
                oacc[0][nt] = mfma16(pa0, vf, oacc[0][nt]);
                oacc[1][nt] = mfma16(pa1, vf, oacc[1][nt]);
            }
        }
        if (kt < 15) {   // commit prefetched tile to buf alt, then barrier
            *(h8*)&KsF[alt][(krow<<6) + 8*((2*c0)     ^ (krow & 7))] = kn0;
            *(h8*)&KsF[alt][(krow<<6) + 8*((2*c0 + 1) ^ (krow & 7))] = kn1;
            #pragma unroll
            for (int i = 0; i < 8; ++i)
                VtsF[alt][((16*vec + i)<<6)     + 8*(vhi ^ i) + vlo] = vn0[i];
            #pragma unroll
            for (int i = 0; i < 8; ++i)
                VtsF[alt][((16*vec + 8 + i)<<6) + 8*(vhi ^ i) + vlo] = vn1[i];
            __syncthreads();
        }
    }

    #pragma unroll
    for (int mt = 0; mt < 2; ++mt)
        #pragma unroll
        for (int r = 0; r < 4; ++r) {
            float s = lp[mt][r];
            s += __shfl_xor(s, 1, 64);
            s += __shfl_xor(s, 2, 64);
            s += __shfl_xor(s, 4, 64);
            s += __shfl_xor(s, 8, 64);
            lp[mt][r] = s;
        }

    _Float16* ob = oa + ((size_t)(b*LL + l0))*(HH*EE) + h*EE;
    #pragma unroll
    for (int mt = 0; mt < 2; ++mt)
        #pragma unroll
        for (int nt = 0; nt < 4; ++nt)
            #pragma unroll
            for (int r = 0; r < 4; ++r) {
                int row = 32*wv + 16*mt + 4*qd + r;
                ob[(size_t)row*(HH*EE) + 16*nt + m] = (_Float16)(oacc[mt][nt][r] / lp[mt][r]);
            }
}

// ---------------- K4: output projection, M128xN128, pipelined ------------
__global__ __launch_bounds__(256) void k_oproj(
    const _Float16* __restrict__ oa, const _Float16* __restrict__ Wo16,
    const float* __restrict__ bo, float* __restrict__ out)
{
    const int y  = blockIdx.x;
    const int r0 = blockIdx.y * 128;

    __shared__ __align__(16) _Float16 As[2][128][72];
    __shared__ __align__(16) _Float16 Bs[2][128][72];

    const int t = threadIdx.x;
    const int wv = t >> 6, lane = t & 63;
    const int m = lane & 15, qd = lane >> 4;
    const int sr = t >> 1, sc0 = (t & 1) * 32;

    const _Float16* ax = oa   + (size_t)(r0 + sr)*DD + sc0;
    const _Float16* bx = Wo16 + (size_t)(y*128 + sr)*DD + sc0;

    #pragma unroll
    for (int c = 0; c < 4; ++c) {
        *(h8*)&As[0][sr][sc0 + 8*c] = *(const h8*)(ax + 8*c);
        *(h8*)&Bs[0][sr][sc0 + 8*c] = *(const h8*)(bx + 8*c);
    }
    __syncthreads();

    f4 acc[2][8] = {};
    int cur = 0;
    for (int kt = 0; kt < 8; ++kt) {
        const int alt = cur ^ 1;
        h8 an[4], bn[4];
        if (kt < 7) {
            const _Float16* a2 = ax + (kt+1)*64;
            const _Float16* b2 = bx + (kt+1)*64;
            #pragma unroll
            for (int c = 0; c < 4; ++c) {
                an[c] = *(const h8*)(a2 + 8*c);
                bn[c] = *(const h8*)(b2 + 8*c);
            }
        }
        #pragma unroll
        for (int ks = 0; ks < 2; ++ks) {
            h8 a0 = *(const h8*)&As[cur][32*wv +  0 + m][32*ks + 8*qd];
            h8 a1 = *(const h8*)&As[cur][32*wv + 16 + m][32*ks + 8*qd];
            #pragma unroll
            for (int nt = 0; nt < 8; ++nt) {
                h8 bb = *(const h8*)&Bs[cur][16*nt + m][32*ks + 8*qd];
                acc[0][nt] = mfma16(a0, bb, acc[0][nt]);
                acc[1][nt] = mfma16(a1, bb, acc[1][nt]);
            }
        }
        if (kt < 7) {
            #pragma unroll
            for (int c = 0; c < 4; ++c) {
                *(h8*)&As[alt][sr][sc0 + 8*c] = an[c];
                *(h8*)&Bs[alt][sr][sc0 + 8*c] = bn[c];
            }
            __syncthreads();
            cur = alt;
        }
    }

    #pragma unroll
    for (int nt = 0; nt < 8; ++nt) {
        const int col = y*128 + 16*nt + m;
        const float bias = bo[col];
        #pragma unroll
        for (int mt = 0; mt < 2; ++mt)
            #pragma unroll
            for (int r = 0; r < 4; ++r) {
                int row = 32*wv + 16*mt + 4*qd + r;
                out[(size_t)(r0 + row)*DD + col] = acc[mt][nt][r] + bias;
            }
    }
}

extern "C" void kernel_launch(void* const* d_in, const int* in_sizes, int n_in,
                              void* d_out, int out_size, void* d_ws, size_t ws_size,
                              hipStream_t stream)
{
    const float* x  = (const float*)d_in[0];
    const int*   pm = (const int*)d_in[1];
    const float* Wq = (const float*)d_in[2];
    const float* Wk = (const float*)d_in[3];
    const float* Wv = (const float*)d_in[4];
    const float* Wo = (const float*)d_in[5];
    const float* bo = (const float*)d_in[6];
    float* out = (float*)d_out;

    const size_t QS = (size_t)BB * HH * LL * EE;
    _Float16* q    = (_Float16*)d_ws;
    _Float16* k    = q + QS;
    _Float16* v    = k + QS;
    _Float16* oaw  = v + QS;
    _Float16* xT   = oaw;              // alias: dead before k_attn writes oaw
    _Float16* WT   = oaw + QS;
    _Float16* Wo16 = WT + (size_t)24*64*DD;
    _Float16* x16  = (_Float16*)d_out; // scratch: dead before k_oproj writes out

    k_x16  <<<dim3(LDX*BB/1024),    256, 0, stream>>>(x, x16);
    k_prep <<<dim3(LDX/256),        256, 0, stream>>>(x, xT);
    k_wprep<<<dim3(8, 24),          256, 0, stream>>>(Wq, Wk, Wv, WT);
    k_wo16 <<<dim3(DD*DD/1024),     256, 0, stream>>>(Wo, Wo16);
    k_qkv  <<<dim3(9, BB*LL/128),   256, 0, stream>>>(x16, WT, q, k, v);
    k_qshuf<<<dim3(LL/4, HH-1),     256, 0, stream>>>(xT, pm, WT, q);
    k_attn <<<dim3(BB*HH, LL/128),  256, 0, stream>>>(q, k, v, oaw);
    k_oproj<<<dim3(DD/128, BB*LL/128), 256, 0, stream>>>(oaw, Wo16, bo, out);
}